// Round 1
// 140.693 us; speedup vs baseline: 1.0004x; 1.0004x over previous
//
#include <hip/hip_runtime.h>
#include <math.h>

// B=16384 rows, C=1000 cols, fp32 -> 16384 fp32. Inputs 131 MB total; the
// harness re-poison fills leave them L3-resident (FETCH_SIZE ~64 MB), so the
// kernel floor is BELOW the 21 us HBM-cold floor.
//
// R4: the R3 "register-resident payload" FAILED — rocprof showed VGPR_Count=28,
// i.e. the compiler still batched the 16 loads (~8 dependent latency round
// trips) and rematerialized them for pass 2. __launch_bounds__ only permits
// VGPRs; it doesn't force liveness. Fix: opaque asm barrier ("+v" on all 32
// payload floats) after the loads. All 16 loads must complete before the asm
// (single latency exposure, 8 KB/wave in flight) and pass 2 reads the asm
// outputs, which cannot be rematerialized from memory.

constexpr int kC  = 1000;
constexpr int kNV = kC / 4;        // 250 float4 per row
constexpr int kRowsPerBlock = 4;

// Pin a float4's lanes into VGPRs: forces the load to have completed here and
// makes the value's provenance opaque (no re-load possible downstream).
#define PIN4(f4) asm volatile("" : "+v"((f4).x), "+v"((f4).y), "+v"((f4).z), "+v"((f4).w))

__global__ __launch_bounds__(256, 4) void netsat_kernel(
    const float* __restrict__ y1, const float* __restrict__ y2,
    float* __restrict__ out, int nrows)
{
    const int lane = threadIdx.x & 63;
    const int wave = threadIdx.x >> 6;
    const int row  = blockIdx.x * kRowsPerBlock + wave;
    if (row >= nrows) return;

    const float4* r1 = reinterpret_cast<const float4*>(y1) + (size_t)row * kNV;
    const float4* r2 = reinterpret_cast<const float4*>(y2) + (size_t)row * kNV;

    // All 16 loads unconditional (tail chunk index-clamped, masked after load).
    const int vi3 = (lane + 192 < kNV) ? (lane + 192) : (kNV - 1);  // clamp
    float4 A[4], B[4];
    A[0] = r1[lane];       B[0] = r2[lane];
    A[1] = r1[lane + 64];  B[1] = r2[lane + 64];
    A[2] = r1[lane + 128]; B[2] = r2[lane + 128];
    A[3] = r1[vi3];        B[3] = r2[vi3];

    const bool tail_ok = (lane + 192) < kNV;
    const float4 ninf4 = make_float4(-INFINITY, -INFINITY, -INFINITY, -INFINITY);
    if (!tail_ok) { A[3] = ninf4; B[3] = ninf4; }   // cndmask, post-load

    // Force the whole 8 KB/wave payload live in VGPRs (64 VGPR) across both
    // passes. Without this the compiler compiles to 28 VGPRs and serializes.
    PIN4(A[0]); PIN4(B[0]); PIN4(A[1]); PIN4(B[1]);
    PIN4(A[2]); PIN4(B[2]); PIN4(A[3]); PIN4(B[3]);

    // ---- pass 1: per-lane branchless top-2 for both inputs ----
    float m1 = -INFINITY, m2 = -INFINITY;
    float n1 = -INFINITY, n2 = -INFINITY;
#pragma unroll
    for (int c = 0; c < 4; ++c) {
        const float* av = reinterpret_cast<const float*>(&A[c]);
        const float* bv = reinterpret_cast<const float*>(&B[c]);
#pragma unroll
        for (int k = 0; k < 4; ++k) {
            const float v = av[k];
            m2 = fmaxf(m2, fminf(m1, v)); m1 = fmaxf(m1, v);
            const float w = bv[k];
            n2 = fmaxf(n2, fminf(n1, w)); n1 = fmaxf(n1, w);
        }
    }

    // ---- wave butterfly: merge (top1, top2); m/n chains interleave (ILP) ----
#pragma unroll
    for (int off = 32; off > 0; off >>= 1) {
        const float o1 = __shfl_xor(m1, off, 64);
        const float o2 = __shfl_xor(m2, off, 64);
        const float p1 = __shfl_xor(n1, off, 64);
        const float p2 = __shfl_xor(n2, off, 64);
        m2 = fmaxf(fminf(m1, o1), fmaxf(m2, o2));
        m1 = fmaxf(m1, o1);
        n2 = fmaxf(fminf(n1, p1), fmaxf(n2, p2));
        n1 = fmaxf(n1, p1);
    }

    // ---- pass 2: max_j min(v - loo1, w - loo2) over REGISTER values ----
    // loo(v) = (v==m1) ? m2 : m1 — tie-safe (duplicated max => m2==m1).
    float best = -INFINITY;
#pragma unroll
    for (int c = 0; c < 4; ++c) {
        const float* av = reinterpret_cast<const float*>(&A[c]);
        const float* bv = reinterpret_cast<const float*>(&B[c]);
#pragma unroll
        for (int k = 0; k < 4; ++k) {
            const float v = av[k];
            const float w = bv[k];
            const float l1 = (v == m1) ? m2 : m1;
            const float l2 = (w == n1) ? n2 : n1;
            best = fmaxf(best, fminf(v - l1, w - l2));
        }
    }
#pragma unroll
    for (int off = 32; off > 0; off >>= 1)
        best = fmaxf(best, __shfl_xor(best, off, 64));

    if (lane == 0) out[row] = best;
}

extern "C" void kernel_launch(void* const* d_in, const int* in_sizes, int n_in,
                              void* d_out, int out_size, void* d_ws, size_t ws_size,
                              hipStream_t stream) {
    const float* y1 = (const float*)d_in[0];
    const float* y2 = (const float*)d_in[1];
    float* out = (float*)d_out;
    const int nrows = out_size;  // 16384
    const int blocks = (nrows + kRowsPerBlock - 1) / kRowsPerBlock;  // 4096
    netsat_kernel<<<blocks, 256, 0, stream>>>(y1, y2, out, nrows);
}

// Round 2
// 140.385 us; speedup vs baseline: 1.0026x; 1.0022x over previous
//
#include <hip/hip_runtime.h>
#include <math.h>

// B=16384 rows, C=1000 cols, fp32 -> 16384 fp32. Inputs 131 MB; harness
// re-poison leaves ~half L3-resident (FETCH_SIZE ~64 MB/dispatch).
//
// R5: structural fix. R3/R4 (one wave per row, 16 float4/wave payload) were
// both defeated by the register allocator (VGPR_Count 28 / 24): loads issued
// in tiny dependent batches + full re-load in pass 2 => ~30k cycles/wave of
// serialized memory latency, 1.5 TB/s HBM. New shape: ONE BLOCK per row,
// 256 threads, each thread owns ONE float4 of y1 + ONE of y2 (8 VGPRs).
// Loads trivially issue together (single latency round); pass 2 reads
// registers by construction; 64K waves give 4x the latency-hiding.
// Cross-wave top-2 merge via 16-float LDS; every thread merges the 4
// wave-results itself (no broadcast barrier needed).

constexpr int kC  = 1000;
constexpr int kNV = kC / 4;        // 250 float4 per row; threads 250..255 pad

__global__ __launch_bounds__(256, 8) void netsat_kernel(
    const float* __restrict__ y1, const float* __restrict__ y2,
    float* __restrict__ out, int nrows)
{
    const int tid  = threadIdx.x;
    const int lane = tid & 63;
    const int wave = tid >> 6;
    const int row  = blockIdx.x;
    if (row >= nrows) return;

    const float4* r1 = reinterpret_cast<const float4*>(y1) + (size_t)row * kNV;
    const float4* r2 = reinterpret_cast<const float4*>(y2) + (size_t)row * kNV;

    // Unconditional clamped loads (branchless), mask pad threads after load.
    const int vi = (tid < kNV) ? tid : (kNV - 1);
    float4 a = r1[vi];
    float4 b = r2[vi];
    if (tid >= kNV) {
        a = make_float4(-INFINITY, -INFINITY, -INFINITY, -INFINITY);
        b = make_float4(-INFINITY, -INFINITY, -INFINITY, -INFINITY);
    }

    // ---- local top-2 over this thread's 4 elements, both inputs ----
    float m1 = -INFINITY, m2 = -INFINITY;   // y1 top-2
    float n1 = -INFINITY, n2 = -INFINITY;   // y2 top-2
    {
        const float* av = reinterpret_cast<const float*>(&a);
        const float* bv = reinterpret_cast<const float*>(&b);
#pragma unroll
        for (int k = 0; k < 4; ++k) {
            const float v = av[k];
            m2 = fmaxf(m2, fminf(m1, v)); m1 = fmaxf(m1, v);
            const float w = bv[k];
            n2 = fmaxf(n2, fminf(n1, w)); n1 = fmaxf(n1, w);
        }
    }

    // ---- wave butterfly merge of (top1, top2); m/n chains interleave ----
#pragma unroll
    for (int off = 32; off > 0; off >>= 1) {
        const float o1 = __shfl_xor(m1, off, 64);
        const float o2 = __shfl_xor(m2, off, 64);
        const float p1 = __shfl_xor(n1, off, 64);
        const float p2 = __shfl_xor(n2, off, 64);
        m2 = fmaxf(fminf(m1, o1), fmaxf(m2, o2));
        m1 = fmaxf(m1, o1);
        n2 = fmaxf(fminf(n1, p1), fmaxf(n2, p2));
        n1 = fmaxf(n1, p1);
    }

    // ---- cross-wave merge via LDS; every thread merges all 4 wave results
    __shared__ float sm[4][4];     // [wave] = {m1, m2, n1, n2}
    __shared__ float sbest[4];
    if (lane == 0) {
        sm[wave][0] = m1; sm[wave][1] = m2;
        sm[wave][2] = n1; sm[wave][3] = n2;
    }
    __syncthreads();

    float M1 = -INFINITY, M2 = -INFINITY, N1 = -INFINITY, N2 = -INFINITY;
#pragma unroll
    for (int w = 0; w < 4; ++w) {
        const float w1 = sm[w][0], w2 = sm[w][1];
        M2 = fmaxf(fminf(M1, w1), fmaxf(M2, w2));
        M1 = fmaxf(M1, w1);
        const float u1 = sm[w][2], u2 = sm[w][3];
        N2 = fmaxf(fminf(N1, u1), fmaxf(N2, u2));
        N1 = fmaxf(N1, u1);
    }

    // ---- pass 2 over REGISTER payload: max_j min(v - loo1, w - loo2) ----
    // loo(v) = (v==M1) ? M2 : M1 — tie-safe (duplicated max => M2==M1).
    float best = -INFINITY;
    {
        const float* av = reinterpret_cast<const float*>(&a);
        const float* bv = reinterpret_cast<const float*>(&b);
#pragma unroll
        for (int k = 0; k < 4; ++k) {
            const float v = av[k];
            const float w = bv[k];
            const float l1 = (v == M1) ? M2 : M1;
            const float l2 = (w == N1) ? N2 : N1;
            best = fmaxf(best, fminf(v - l1, w - l2));
        }
    }
#pragma unroll
    for (int off = 32; off > 0; off >>= 1)
        best = fmaxf(best, __shfl_xor(best, off, 64));

    if (lane == 0) sbest[wave] = best;
    __syncthreads();

    if (tid == 0) {
        float r = fmaxf(fmaxf(sbest[0], sbest[1]), fmaxf(sbest[2], sbest[3]));
        out[row] = r;
    }
}

extern "C" void kernel_launch(void* const* d_in, const int* in_sizes, int n_in,
                              void* d_out, int out_size, void* d_ws, size_t ws_size,
                              hipStream_t stream) {
    const float* y1 = (const float*)d_in[0];
    const float* y2 = (const float*)d_in[1];
    float* out = (float*)d_out;
    const int nrows = out_size;  // 16384
    netsat_kernel<<<nrows, 256, 0, stream>>>(y1, y2, out, nrows);
}